// Round 6
// baseline (236.505 us; speedup 1.0000x reference)
//
#include <hip/hip_runtime.h>
#include <hip/hip_bf16.h>
#include <stdint.h>

// B=8, N=1024, D=256, fp32 in/out.
// R6: mega v2 — 16-row strips (grid 512, 2 blocks/CU, acc=128 VGPR instead of
// 256) so the compiler can pipeline the direct-global B loads; static LDS.
// prep fused into one dispatch (pos + x-split + y-prep + M-build). 3 launches.

#define NB 8
#define NN_ 1024
#define ND 256

typedef __bf16 bf16x8 __attribute__((ext_vector_type(8)));
typedef __bf16 bf16x4 __attribute__((ext_vector_type(4)));
typedef float f32x4 __attribute__((ext_vector_type(4)));

// ---------------- async global->LDS (16B per lane) -- used by xs mgemm ------
__device__ inline void gl_lds(const __bf16* g, __bf16* l) {
    auto gp = (const __attribute__((address_space(1))) uint32_t*)(uintptr_t)g;
    auto lp = (__attribute__((address_space(3))) uint32_t*)(uintptr_t)l;
    __builtin_amdgcn_global_load_lds(gp, lp, 16, 0, 0);
}

// ---------------- reductions ----------------
__device__ inline float wred_sum(float v) {
#pragma unroll
    for (int o = 32; o; o >>= 1) v += __shfl_xor(v, o, 64);
    return v;
}
__device__ inline float wred_max(float v) {
#pragma unroll
    for (int o = 32; o; o >>= 1) v = fmaxf(v, __shfl_xor(v, o, 64));
    return v;
}

// ---------------- fused prep: pos softmax | x split | y prep | build M ------
// grid: [0,1024) pos rows; [1024,1536) x-split; [1536,2048) y-prep;
//       [2048,2304) build_M.
__global__ __launch_bounds__(256) void prep_kernel(
    const float* __restrict__ coords, const float* __restrict__ pos_emb,
    const float* __restrict__ p_temp, const float* __restrict__ x,
    const float* __restrict__ y, const float* __restrict__ U,
    const float* __restrict__ S1, const float* __restrict__ S2,
    float* __restrict__ posS, __bf16* __restrict__ Xh, __bf16* __restrict__ Xl,
    __bf16* __restrict__ yt, __bf16* __restrict__ Yh, __bf16* __restrict__ Yl,
    __bf16* __restrict__ Mh, __bf16* __restrict__ Ml) {
    __shared__ char sm[9216 + 64];
    const int bid = blockIdx.x;
    const int tid = threadIdx.x;

    if (bid < 1024) {
        // ---- pos softmax row n = bid ----
        float* red = (float*)sm;
        const int n = bid;
        const float pt = -fabsf(p_temp[0]);
        float pe[6];
#pragma unroll
        for (int c = 0; c < 6; ++c) pe[c] = pos_emb[n * 6 + c];
        const float* cr = coords + (long)n * NN_ * 6;
        float l[4];
#pragma unroll
        for (int j = 0; j < 4; ++j) {
            const int m = j * 256 + tid;
            const float2* cp = (const float2*)(cr + (long)m * 6);
            float2 c0 = cp[0], c1 = cp[1], c2 = cp[2];
            l[j] = pt * (c0.x * pe[0] + c0.y * pe[1] + c1.x * pe[2] +
                         c1.y * pe[3] + c2.x * pe[4] + c2.y * pe[5]);
        }
        float mx = fmaxf(fmaxf(l[0], l[1]), fmaxf(l[2], l[3]));
        mx = wred_max(mx);
        __syncthreads();
        if ((tid & 63) == 0) red[tid >> 6] = mx;
        __syncthreads();
        mx = fmaxf(fmaxf(red[0], red[1]), fmaxf(red[2], red[3]));
        float e[4], s = 0.f;
#pragma unroll
        for (int j = 0; j < 4; ++j) { e[j] = __expf(l[j] - mx); s += e[j]; }
        s = wred_sum(s);
        __syncthreads();
        if ((tid & 63) == 0) red[4 + (tid >> 6)] = s;
        __syncthreads();
        s = red[4] + red[5] + red[6] + red[7];
        const float inv = 1.f / s;
#pragma unroll
        for (int j = 0; j < 4; ++j)
            posS[(long)n * NN_ + j * 256 + tid] = e[j] * inv;
    } else if (bid < 1536) {
        // ---- x -> bf16 hi/lo ----
        const int n4 = NB * NN_ * ND / 4;
        int i = (bid - 1024) * 256 + tid;
        for (; i < n4; i += 512 * 256) {
            float4 v = ((const float4*)x)[i];
            bf16x4 h, l;
            h[0] = (__bf16)v.x; l[0] = (__bf16)(v.x - (float)h[0]);
            h[1] = (__bf16)v.y; l[1] = (__bf16)(v.y - (float)h[1]);
            h[2] = (__bf16)v.z; l[2] = (__bf16)(v.z - (float)h[2]);
            h[3] = (__bf16)v.w; l[3] = (__bf16)(v.w - (float)h[3]);
            ((bf16x4*)Xh)[i] = h;
            ((bf16x4*)Xl)[i] = l;
        }
    } else if (bid < 2048) {
        // ---- y: yt (bf16 transposed) + hi/lo split ----
        __bf16 (*t)[72] = (__bf16(*)[72])sm;
        const int rem = bid - 1536;
        const int b = rem >> 6;
        const int m0 = (rem & 15) * 64, d0 = ((rem >> 4) & 3) * 64;
        const int c = tid & 15;
        const int r = tid >> 4;
#pragma unroll
        for (int p = 0; p < 4; ++p) {
            const int row = r + p * 16;
            const long gi = ((long)b * NN_ + m0 + row) * ND + d0 + c * 4;
            float4 v = *(const float4*)(y + gi);
            bf16x4 h, l;
            h[0] = (__bf16)v.x; l[0] = (__bf16)(v.x - (float)h[0]);
            h[1] = (__bf16)v.y; l[1] = (__bf16)(v.y - (float)h[1]);
            h[2] = (__bf16)v.z; l[2] = (__bf16)(v.z - (float)h[2]);
            h[3] = (__bf16)v.w; l[3] = (__bf16)(v.w - (float)h[3]);
            *(bf16x4*)(Yh + gi) = h;
            *(bf16x4*)(Yl + gi) = l;
            t[c * 4 + 0][row] = h[0]; t[c * 4 + 1][row] = h[1];
            t[c * 4 + 2][row] = h[2]; t[c * 4 + 3][row] = h[3];
        }
        __syncthreads();
#pragma unroll
        for (int p = 0; p < 4; ++p) {
            const int d = r + p * 16;
            bf16x4 o;
            o[0] = t[d][c * 4 + 0]; o[1] = t[d][c * 4 + 1];
            o[2] = t[d][c * 4 + 2]; o[3] = t[d][c * 4 + 3];
            *(bf16x4*)(yt + ((long)b * ND + d0 + d) * NN_ + m0 + c * 4) = o;
        }
    } else {
        // ---- M_k = U^T diag|S_k| U, split hi/lo ----
        const int n = bid - 2048, j = tid;
        float a1 = 0.f, a2 = 0.f;
        for (int c = 0; c < ND; ++c) {
            const float un = U[c * ND + n];
            const float uj = U[c * ND + j];
            a1 = fmaf(fabsf(S1[c]) * un, uj, a1);
            a2 = fmaf(fabsf(S2[c]) * un, uj, a2);
        }
        const __bf16 h1 = (__bf16)a1, h2 = (__bf16)a2;
        Mh[n * ND + j] = h1;           Ml[n * ND + j] = (__bf16)(a1 - (float)h1);
        Mh[65536 + n * ND + j] = h2;   Ml[65536 + n * ND + j] = (__bf16)(a2 - (float)h2);
    }
}

// ---------------- MFMA GEMM (xs = x @ M_k), global_load_lds staged ----------
template <int BN, bool SPLIT, int OUTM>
__global__ __launch_bounds__(256) void mgemm(
    const __bf16* __restrict__ Ah, const __bf16* __restrict__ Al,
    const __bf16* __restrict__ Bh, const __bf16* __restrict__ Bl,
    float* __restrict__ C, __bf16* __restrict__ Ch, __bf16* __restrict__ Cl,
    int M, int N, int K,
    long sA1, long sA2, int divA, long sB1, int divB, long sC, float alpha) {
    constexpr int BM = 128, BK = 32;
    constexpr int NBUF = SPLIT ? 2 : 1;
    constexpr int NF = BN / 32;
    __shared__ __bf16 As[NBUF * BM * BK];
    __shared__ __bf16 Bs[NBUF * BN * BK];

    const int z = blockIdx.z;
    const long aoff = (long)(z / divA) * sA1 + (long)(z % divA) * sA2;
    const long boff = (long)(z / divB) * sB1;
    Ah += aoff; if (SPLIT) Al += aoff;
    Bh += boff; if (SPLIT) Bl += boff;

    const int tid = threadIdx.x;
    const int bm = blockIdx.y * BM, bn = blockIdx.x * BN;
    const int wave = tid >> 6, lane = tid & 63;
    const int wm = wave >> 1, wn = wave & 1;
    const int quad = lane >> 4, l16 = lane & 15;

    f32x4 acc[4][NF];
#pragma unroll
    for (int i = 0; i < 4; ++i)
#pragma unroll
        for (int j = 0; j < NF; ++j) acc[i][j] = (f32x4){0.f, 0.f, 0.f, 0.f};

    const int srow = lane >> 2;
    const int slot = lane & 3;

    for (int k0 = 0; k0 < K; k0 += BK) {
        __syncthreads();
#pragma unroll
        for (int i = 0; i < 2; ++i) {
            const int r0 = wave * 32 + i * 16;
            const int row = r0 + srow;
            const int chunk = slot ^ ((row >> 1) & 3);
            const long g = (long)(bm + row) * K + k0 + chunk * 8;
            gl_lds(Ah + g, &As[r0 * 32]);
            if (SPLIT) gl_lds(Al + g, &As[BM * BK + r0 * 32]);
        }
        if (BN == 128) {
#pragma unroll
            for (int i = 0; i < 2; ++i) {
                const int r0 = wave * 32 + i * 16;
                const int row = r0 + srow;
                const int chunk = slot ^ ((row >> 1) & 3);
                const long g = (long)(bn + row) * K + k0 + chunk * 8;
                gl_lds(Bh + g, &Bs[r0 * 32]);
                if (SPLIT) gl_lds(Bl + g, &Bs[BN * BK + r0 * 32]);
            }
        } else {
            const int r0 = wave * 16;
            const int row = r0 + srow;
            const int chunk = slot ^ ((row >> 1) & 3);
            const long g = (long)(bn + row) * K + k0 + chunk * 8;
            gl_lds(Bh + g, &Bs[r0 * 32]);
            if (SPLIT) gl_lds(Bl + g, &Bs[BN * BK + r0 * 32]);
        }
        __syncthreads();

        bf16x8 a_h[4], a_l[4], b_h[NF], b_l[NF];
#pragma unroll
        for (int mi = 0; mi < 4; ++mi) {
            const int row = wm * 64 + mi * 16 + l16;
            const int off = row * 32 + ((quad ^ ((row >> 1) & 3)) * 8);
            a_h[mi] = *(const bf16x8*)&As[off];
            if (SPLIT) a_l[mi] = *(const bf16x8*)&As[BM * BK + off];
        }
#pragma unroll
        for (int ni = 0; ni < NF; ++ni) {
            const int row = wn * (BN / 2) + ni * 16 + l16;
            const int off = row * 32 + ((quad ^ ((row >> 1) & 3)) * 8);
            b_h[ni] = *(const bf16x8*)&Bs[off];
            if (SPLIT) b_l[ni] = *(const bf16x8*)&Bs[BN * BK + off];
        }
#pragma unroll
        for (int mi = 0; mi < 4; ++mi)
#pragma unroll
            for (int ni = 0; ni < NF; ++ni) {
                acc[mi][ni] = __builtin_amdgcn_mfma_f32_16x16x32_bf16(
                    a_h[mi], b_h[ni], acc[mi][ni], 0, 0, 0);
                if (SPLIT) {
                    acc[mi][ni] = __builtin_amdgcn_mfma_f32_16x16x32_bf16(
                        a_h[mi], b_l[ni], acc[mi][ni], 0, 0, 0);
                    acc[mi][ni] = __builtin_amdgcn_mfma_f32_16x16x32_bf16(
                        a_l[mi], b_h[ni], acc[mi][ni], 0, 0, 0);
                }
            }
    }

    C += (long)z * sC; Ch += (long)z * sC; Cl += (long)z * sC;
#pragma unroll
    for (int mi = 0; mi < 4; ++mi) {
        const int row0 = bm + wm * 64 + mi * 16 + quad * 4;
#pragma unroll
        for (int ni = 0; ni < NF; ++ni) {
            const int col = bn + wn * (BN / 2) + ni * 16 + l16;
#pragma unroll
            for (int r = 0; r < 4; ++r) {
                const float v = acc[mi][ni][r] * alpha;
                const long idx = (long)(row0 + r) * N + col;
                if (OUTM == 0) {
                    C[idx] = v;
                } else {
                    const __bf16 h = (__bf16)v;
                    Ch[idx] = h;
                    Cl[idx] = (__bf16)(v - (float)h);
                }
            }
        }
    }
}

// ---------------- MEGA v2: 16-row strips, 2 blocks/CU ----------------------
// Block = 256 thr (4 waves), b = blk&7, rows n0..n0+15, wave w cols [w*256,+256).
// acc[2 branches][16 ni] = 128 VGPR. A/B frags direct-global (L2-resident).
__global__ __launch_bounds__(256, 2) void mega_kernel(
    const __bf16* __restrict__ XSh, const __bf16* __restrict__ XSl,
    const __bf16* __restrict__ Yh, const __bf16* __restrict__ Yl,
    const __bf16* __restrict__ yt, const float* __restrict__ pos,
    const float* __restrict__ gating, const float* __restrict__ h_temp,
    float* __restrict__ heat, float* __restrict__ out) {
    __shared__ __bf16 Pl[16 * 1032];              // 33 KB, stride 1032 (uniform banks)
    __shared__ float red0[128], red1[128], red2[128];

    const int b  = blockIdx.x & 7;
    const int n0 = (blockIdx.x >> 3) * 16;
    const int tid = threadIdx.x;
    const int wave = tid >> 6, lane = tid & 63;
    const int quad = lane >> 4, l16 = lane & 15;
    const int wcol = wave * 256;
    const long BNDe = (long)NB * NN_ * ND;

    const __bf16* Ahp = XSh + ((long)b * NN_ + n0) * ND;
    const __bf16* Alp = XSl + ((long)b * NN_ + n0) * ND;
    const __bf16* Bhp = Yh + ((long)b * NN_ + wcol) * ND;
    const __bf16* Blp = Yl + ((long)b * NN_ + wcol) * ND;

    f32x4 acc[2][16];
#pragma unroll
    for (int br = 0; br < 2; ++br)
#pragma unroll
        for (int ni = 0; ni < 16; ++ni) acc[br][ni] = (f32x4){0.f, 0.f, 0.f, 0.f};

    // ---- scores K-loop: direct-global fragments, no barriers ----
    for (int k0 = 0; k0 < ND; k0 += 32) {
        bf16x8 ah[2], al[2];
#pragma unroll
        for (int br = 0; br < 2; ++br) {
            const long o = (long)br * BNDe + (long)l16 * ND + k0 + quad * 8;
            ah[br] = *(const bf16x8*)(Ahp + o);
            al[br] = *(const bf16x8*)(Alp + o);
        }
#pragma unroll
        for (int ni = 0; ni < 16; ++ni) {
            const long o = (long)(ni * 16 + l16) * ND + k0 + quad * 8;
            bf16x8 bh = *(const bf16x8*)(Bhp + o);
            bf16x8 bl = *(const bf16x8*)(Blp + o);
#pragma unroll
            for (int br = 0; br < 2; ++br) {
                acc[br][ni] = __builtin_amdgcn_mfma_f32_16x16x32_bf16(
                    ah[br], bh, acc[br][ni], 0, 0, 0);
                acc[br][ni] = __builtin_amdgcn_mfma_f32_16x16x32_bf16(
                    ah[br], bl, acc[br][ni], 0, 0, 0);
                acc[br][ni] = __builtin_amdgcn_mfma_f32_16x16x32_bf16(
                    al[br], bh, acc[br][ni], 0, 0, 0);
            }
        }
    }

    // ---- scale + row max (rows live in (quad, rr); reduce over ni, l16) ----
    float mx[2][4];
#pragma unroll
    for (int br = 0; br < 2; ++br)
#pragma unroll
        for (int rr = 0; rr < 4; ++rr) {
            float m = -3.4e38f;
#pragma unroll
            for (int ni = 0; ni < 16; ++ni) {
                acc[br][ni][rr] *= 0.0625f;
                m = fmaxf(m, acc[br][ni][rr]);
            }
            mx[br][rr] = m;
        }
#pragma unroll
    for (int o = 1; o < 16; o <<= 1)
#pragma unroll
        for (int br = 0; br < 2; ++br)
#pragma unroll
            for (int rr = 0; rr < 4; ++rr)
                mx[br][rr] = fmaxf(mx[br][rr], __shfl_xor(mx[br][rr], o, 64));
    if (l16 == 0)
#pragma unroll
        for (int br = 0; br < 2; ++br)
#pragma unroll
            for (int rr = 0; rr < 4; ++rr)
                red0[(wave * 2 + br) * 16 + quad * 4 + rr] = mx[br][rr];
    __syncthreads();
#pragma unroll
    for (int br = 0; br < 2; ++br)
#pragma unroll
        for (int rr = 0; rr < 4; ++rr) {
            const int ri = quad * 4 + rr;
            float m = red0[(0 + br) * 16 + ri];
            m = fmaxf(m, red0[(2 + br) * 16 + ri]);
            m = fmaxf(m, red0[(4 + br) * 16 + ri]);
            m = fmaxf(m, red0[(6 + br) * 16 + ri]);
            mx[br][rr] = m;
        }

    // ---- exp in place + row sum ----
    float sm[2][4];
#pragma unroll
    for (int br = 0; br < 2; ++br)
#pragma unroll
        for (int rr = 0; rr < 4; ++rr) {
            float s = 0.f;
#pragma unroll
            for (int ni = 0; ni < 16; ++ni) {
                const float e = __expf(acc[br][ni][rr] - mx[br][rr]);
                acc[br][ni][rr] = e;
                s += e;
            }
            sm[br][rr] = s;
        }
#pragma unroll
    for (int o = 1; o < 16; o <<= 1)
#pragma unroll
        for (int br = 0; br < 2; ++br)
#pragma unroll
            for (int rr = 0; rr < 4; ++rr)
                sm[br][rr] += __shfl_xor(sm[br][rr], o, 64);
    if (l16 == 0)
#pragma unroll
        for (int br = 0; br < 2; ++br)
#pragma unroll
            for (int rr = 0; rr < 4; ++rr)
                red1[(wave * 2 + br) * 16 + quad * 4 + rr] = sm[br][rr];
    __syncthreads();
    float inv[2][4];
#pragma unroll
    for (int br = 0; br < 2; ++br)
#pragma unroll
        for (int rr = 0; rr < 4; ++rr) {
            const int ri = quad * 4 + rr;
            const float s = red1[(0 + br) * 16 + ri] + red1[(2 + br) * 16 + ri] +
                            red1[(4 + br) * 16 + ri] + red1[(6 + br) * 16 + ri];
            inv[br][rr] = 1.f / s;
        }

    // ---- blend + entropy ----
    const float g = 1.f / (1.f + __expf(-gating[0]));
    const float cg = 1.f - g;
    float ent[2][4];
#pragma unroll
    for (int br = 0; br < 2; ++br)
#pragma unroll
        for (int rr = 0; rr < 4; ++rr) ent[br][rr] = 0.f;
#pragma unroll
    for (int ni = 0; ni < 16; ++ni)
#pragma unroll
        for (int rr = 0; rr < 4; ++rr) {
            const int ri = quad * 4 + rr;
            const float pv = pos[(long)(n0 + ri) * NN_ + wcol + ni * 16 + l16];
#pragma unroll
            for (int br = 0; br < 2; ++br) {
                const float a = cg * acc[br][ni][rr] * inv[br][rr] + g * pv;
                acc[br][ni][rr] = a;
                ent[br][rr] -= a * __logf(a + 1e-8f);
            }
        }
#pragma unroll
    for (int o = 1; o < 16; o <<= 1)
#pragma unroll
        for (int br = 0; br < 2; ++br)
#pragma unroll
            for (int rr = 0; rr < 4; ++rr)
                ent[br][rr] += __shfl_xor(ent[br][rr], o, 64);
    if (l16 == 0)
#pragma unroll
        for (int br = 0; br < 2; ++br)
#pragma unroll
            for (int rr = 0; rr < 4; ++rr)
                red2[(wave * 2 + br) * 16 + quad * 4 + rr] = ent[br][rr];
    __syncthreads();

    // ---- route + heat + selected P -> LDS ----
    const float ht = h_temp[0];
    float fsel[4];
#pragma unroll
    for (int rr = 0; rr < 4; ++rr) {
        const int ri = quad * 4 + rr;
        const float e0 = red2[0 + ri] + red2[32 + ri] + red2[64 + ri] + red2[96 + ri];
        const float e1 = red2[16 + ri] + red2[48 + ri] + red2[80 + ri] + red2[112 + ri];
        const float hm0 = 2.f - 2.f / (1.f + __expf(-ht * e0));
        const float hm1 = 2.f - 2.f / (1.f + __expf(-ht * e1));
        const bool fg = (hm0 >= hm1);
        fsel[rr] = fg ? 1.f : 0.f;
        if (wave == 0 && l16 == 0)
            heat[(long)b * NN_ + n0 + ri] = fg ? hm0 : hm1;
    }
#pragma unroll
    for (int ni = 0; ni < 16; ++ni)
#pragma unroll
        for (int rr = 0; rr < 4; ++rr) {
            const int ri = quad * 4 + rr;
            const float v = fsel[rr] != 0.f ? acc[0][ni][rr] : acc[1][ni][rr];
            Pl[ri * 1032 + wcol + ni * 16 + l16] = (__bf16)v;
        }
    __syncthreads();

    // ---- fused out GEMM: out[16 x 256] = P(LDS) @ yt^T; wave d-slice 64 ----
    f32x4 oacc[4];
#pragma unroll
    for (int nd = 0; nd < 4; ++nd) oacc[nd] = (f32x4){0.f, 0.f, 0.f, 0.f};
    const __bf16* Bo = yt + ((long)b * ND + wave * 64) * NN_;
    for (int k0 = 0; k0 < NN_; k0 += 32) {
        bf16x8 pa = *(const bf16x8*)&Pl[l16 * 1032 + k0 + quad * 8];
#pragma unroll
        for (int nd = 0; nd < 4; ++nd) {
            bf16x8 bo = *(const bf16x8*)(Bo + (long)(nd * 16 + l16) * NN_ + k0 + quad * 8);
            oacc[nd] = __builtin_amdgcn_mfma_f32_16x16x32_bf16(pa, bo, oacc[nd], 0, 0, 0);
        }
    }
#pragma unroll
    for (int nd = 0; nd < 4; ++nd)
#pragma unroll
        for (int r = 0; r < 4; ++r)
            out[((long)b * NN_ + n0 + quad * 4 + r) * ND +
                wave * 64 + nd * 16 + l16] = oacc[nd][r];
}

extern "C" void kernel_launch(void* const* d_in, const int* in_sizes, int n_in,
                              void* d_out, int out_size, void* d_ws, size_t ws_size,
                              hipStream_t stream) {
    const float* x      = (const float*)d_in[0];
    const float* y      = (const float*)d_in[1];
    const float* coords = (const float*)d_in[2];
    const float* U      = (const float*)d_in[3];
    const float* S1p    = (const float*)d_in[4];
    const float* S2p    = (const float*)d_in[5];
    const float* gating = (const float*)d_in[6];
    const float* h_temp = (const float*)d_in[7];
    const float* p_temp = (const float*)d_in[8];
    const float* pos_emb= (const float*)d_in[9];

    float* out  = (float*)d_out;
    float* heat = out + (long)NB * NN_ * ND;

    // workspace (~41 MB)
    char* ws = (char*)d_ws;
    const long MB = 1 << 20;
    float*  pos = (float*)(ws);               // 4 MB
    __bf16* Xh  = (__bf16*)(ws + 4 * MB);     // 4 MB
    __bf16* Xl  = (__bf16*)(ws + 8 * MB);     // 4 MB
    __bf16* XSh = (__bf16*)(ws + 12 * MB);    // 8 MB [2][8192][256]
    __bf16* XSl = (__bf16*)(ws + 20 * MB);    // 8 MB
    __bf16* yt  = (__bf16*)(ws + 28 * MB);    // 4 MB [8][256][1024]
    __bf16* Yh  = (__bf16*)(ws + 32 * MB);    // 4 MB
    __bf16* Yl  = (__bf16*)(ws + 36 * MB);    // 4 MB
    __bf16* Mh  = (__bf16*)(ws + 40 * MB);    // 256 KB [2][256][256]
    __bf16* Ml  = Mh + 2 * 65536;             // 256 KB

    const long BND = (long)NB * NN_ * ND;     // 2097152

    // 1) fused prep
    prep_kernel<<<dim3(2304), 256, 0, stream>>>(
        coords, pos_emb, p_temp, x, y, U, S1p, S2p,
        pos, Xh, Xl, yt, Yh, Yl, Mh, Ml);

    // 2) xs_k = x @ M_k  (z=k) -> XS [2][8192][256]
    mgemm<64, true, 1><<<dim3(4, 64, 2), 256, 0, stream>>>(
        Xh, Xl, Mh, Ml, nullptr, XSh, XSl, NB * NN_, ND, ND,
        0, 0, 1, 65536, 1, BND, 1.0f);

    // 3) mega: scores + softmax + blend + entropy + route + out
    mega_kernel<<<dim3(512), 256, 0, stream>>>(
        XSh, XSl, Yh, Yl, yt, pos, gating, h_temp, heat, out);

    (void)in_sizes; (void)n_in; (void)out_size; (void)ws_size;
}